// Round 3
// baseline (107.525 us; speedup 1.0000x reference)
//
#include <hip/hip_runtime.h>
#include <cstdint>
#include <cmath>

typedef unsigned short u16;
typedef __bf16 bf16x8 __attribute__((ext_vector_type(8)));
typedef float f32x4 __attribute__((ext_vector_type(4)));

#define B_SZ   1024
#define IN_SZ  512
#define U_SZ   512
#define KTOT   4608      // IN_SZ * 9 (8 spline bases + 1 silu slot)
#define SPLITS 16
#define KLEN   288       // KTOT / SPLITS
#define BK     32
#define KITERS 9         // KLEN / BK

__device__ __forceinline__ u16 f2bf(float f) {
  __bf16 h = (__bf16)f;
  return __builtin_bit_cast(u16, h);
}

// async global->LDS, 16B per lane. LDS dest must be wave-uniform base + lane*16.
__device__ __forceinline__ void async16(const void* g, void* l) {
  __builtin_amdgcn_global_load_lds(
      (__attribute__((address_space(1))) void*)(g),
      (__attribute__((address_space(3))) void*)(l), 16u, 0, 0u);
}

// ---------------------------------------------------------------------------
// One fused prep launch, grid-partitioned by blockIdx.x:
//   [0,512):    W'[o][i*9+k] = (k<8 ? SK[i][k][o] : 1)*SF[i][o], O-major (LDS
//               transpose, pad 66 so the strided read is conflict-free)
//   [512,2560): A[b][i*9+k] = cubic B-spline bases + silu (LDS-staged so the
//               global write is coalesced u16 streams, not 9x2B scalar)
//   [2560,3072): out[b][o] = bias[o]  (f32x4)
// ---------------------------------------------------------------------------
__global__ void __launch_bounds__(256) prep_all(const float* __restrict__ SK,
                                                const float* __restrict__ SF,
                                                const float* __restrict__ X,
                                                const float* __restrict__ bias,
                                                u16* __restrict__ WT,
                                                u16* __restrict__ A,
                                                float* __restrict__ out) {
  const int bx = blockIdx.x;
  const int tid = threadIdx.x;

  if (bx < 512) {
    __shared__ u16 tile[72 * 66];
    const int o0 = (bx & 7) * 64;
    const int i0 = (bx >> 3) * 8;
    const int oo = tid & 63, grp = tid >> 6;
    for (int tr = grp; tr < 72; tr += 4) {
      int i = i0 + tr / 9;
      int k = tr % 9;
      float sf = SF[(size_t)i * U_SZ + o0 + oo];
      float v  = (k < 8) ? SK[((size_t)i * 8 + k) * U_SZ + o0 + oo] * sf : sf;
      tile[tr * 66 + oo] = f2bf(v);
    }
    __syncthreads();
    const int t0 = i0 * 9;
    for (int idx = tid; idx < 72 * 64; idx += 256) {
      int ol = idx / 72;
      int c  = idx - ol * 72;
      WT[(size_t)(o0 + ol) * KTOT + t0 + c] = tile[c * 66 + ol];
    }
  } else if (bx < 2560) {
    __shared__ u16 st[2304];
    const int gid0 = (bx - 512) * 256;          // first (b*512+i) of this block
    const float x = X[gid0 + tid];

    const float T0 = -2.2f, H = 0.4f;
    float b0[11], b1[10], b2[9], b3[8];
#pragma unroll
    for (int j = 0; j < 11; ++j) {
      float tj  = T0 + H * j;
      float tj1 = T0 + H * (j + 1);
      b0[j] = (x >= tj && x < tj1) ? 1.0f : 0.0f;
    }
#pragma unroll
    for (int j = 0; j < 10; ++j) {
      float tj  = T0 + H * j;
      float tj2 = T0 + H * (j + 2);
      b1[j] = (x - tj) * 2.5f * b0[j] + (tj2 - x) * 2.5f * b0[j + 1];
    }
#pragma unroll
    for (int j = 0; j < 9; ++j) {
      float tj  = T0 + H * j;
      float tj3 = T0 + H * (j + 3);
      b2[j] = (x - tj) * 1.25f * b1[j] + (tj3 - x) * 1.25f * b1[j + 1];
    }
#pragma unroll
    for (int j = 0; j < 8; ++j) {
      float tj  = T0 + H * j;
      float tj4 = T0 + H * (j + 4);
      b3[j] = (x - tj) * (1.0f / 1.2f) * b2[j] + (tj4 - x) * (1.0f / 1.2f) * b2[j + 1];
    }
    float sil = x / (1.0f + expf(-x));

#pragma unroll
    for (int k = 0; k < 8; ++k) st[tid * 9 + k] = f2bf(b3[k]);
    st[tid * 9 + 8] = f2bf(sil);
    __syncthreads();
    u16* dst = A + (size_t)gid0 * 9;
#pragma unroll
    for (int j = 0; j < 9; ++j) dst[j * 256 + tid] = st[j * 256 + tid];
  } else {
    const int idx = (bx - 2560) * 256 + tid;    // f32x4 index, 0..131071
    ((f32x4*)out)[idx] = ((const f32x4*)bias)[idx & 127];
  }
}

// ---------------------------------------------------------------------------
// Split-K bf16 MFMA GEMM: out (+)= A[m0:+128, ks] * WT[n0:+128, ks]^T
// 256 threads = 4 waves in 2x2; each wave a 64x64 subtile (4x4 frags of
// 16x16x32). BK=32, double-buffered LDS with XOR-chunk swizzle (bank-optimal
// frag reads), global_load_lds width-16 staging. Epilogue: HW fp32 atomic
// add directly into out (pre-initialized with bias) — no partial buffer,
// no reduce kernel. grid (8,4,16) x 256.
// ---------------------------------------------------------------------------
__global__ void __launch_bounds__(256) gemm_kan(const u16* __restrict__ A,
                                                const u16* __restrict__ WT,
                                                float* __restrict__ out) {
  __shared__ __align__(16) u16 sA[2][128 * BK];   // 8 KB each buf
  __shared__ __align__(16) u16 sB[2][128 * BK];

  const int t    = threadIdx.x;
  const int lane = t & 63;
  const int w    = t >> 6;
  const int wr   = w >> 1;          // wave m-half (0/1)
  const int wn   = w & 1;           // wave n-half (0/1)
  const int m0   = blockIdx.x * 128;
  const int n0   = blockIdx.y * 128;
  const int kbase = blockIdx.z * KLEN;

  // staging: idx = j*256+t -> (row = idx>>2, c = idx&3); LDS pos (row,c) gets
  // global chunk g = c ^ (row&3). Dest offset idx*16 = wave-uniform + lane*16.
  const int srow = t >> 2, sc = t & 3;
  const int sg0 = (sc ^ (srow & 3)) * 8;              // element offset of chunk
  const int srow1 = (t + 256) >> 2, sc1 = t & 3;      // j=1: row += 64
  const int sg1 = (sc1 ^ (srow1 & 3)) * 8;
  const u16* gA0 = A  + (size_t)(m0 + srow)  * KTOT + sg0;
  const u16* gA1 = A  + (size_t)(m0 + srow1) * KTOT + sg1;
  const u16* gB0 = WT + (size_t)(n0 + srow)  * KTOT + sg0;
  const u16* gB1 = WT + (size_t)(n0 + srow1) * KTOT + sg1;

  f32x4 acc[4][4];
#pragma unroll
  for (int i = 0; i < 4; ++i)
#pragma unroll
    for (int j = 0; j < 4; ++j) acc[i][j] = (f32x4)0.0f;

  auto stage = [&](int buf, int k0) {
    char* lA = (char*)(&sA[buf][0]) + t * 16;
    char* lB = (char*)(&sB[buf][0]) + t * 16;
    async16(gA0 + k0, lA);
    async16(gA1 + k0, lA + 4096);
    async16(gB0 + k0, lB);
    async16(gB1 + k0, lB + 4096);
  };

  stage(0, kbase);

  const int m = lane & 15, q = lane >> 4;
  // frag read: row = half*64 + tt*16 + m; chunk pos = q ^ (row&3) = q ^ (m&3)
  const int qs = (q ^ (m & 3)) * 16;   // byte offset within row
  const char* fA = (const char*)(&sA[0][0]) + (wr * 64 + m) * (BK * 2) + qs;
  const char* fB = (const char*)(&sB[0][0]) + (wn * 64 + m) * (BK * 2) + qs;
  const int bufstep = 128 * BK * 2;    // bytes between dbuf buffers

#pragma unroll
  for (int it = 0; it < KITERS; ++it) {
    const int cur = it & 1;
    __syncthreads();                   // drains vmcnt: buf[cur] ready
    if (it + 1 < KITERS) stage(cur ^ 1, kbase + (it + 1) * BK);

    bf16x8 af[4], bfv[4];
#pragma unroll
    for (int tt = 0; tt < 4; ++tt)
      af[tt] = *(const bf16x8*)(fA + cur * bufstep + tt * 16 * (BK * 2));
#pragma unroll
    for (int tt = 0; tt < 4; ++tt)
      bfv[tt] = *(const bf16x8*)(fB + cur * bufstep + tt * 16 * (BK * 2));
#pragma unroll
    for (int mt = 0; mt < 4; ++mt)
#pragma unroll
      for (int nt = 0; nt < 4; ++nt)
        acc[mt][nt] = __builtin_amdgcn_mfma_f32_16x16x32_bf16(
            af[mt], bfv[nt], acc[mt][nt], 0, 0, 0);
  }

  // epilogue: C/D layout col = lane&15, row = (lane>>4)*4 + reg.
  // HW fp32 atomic add into bias-initialized out.
#pragma unroll
  for (int mt = 0; mt < 4; ++mt)
#pragma unroll
    for (int rr = 0; rr < 4; ++rr) {
      int row = m0 + wr * 64 + mt * 16 + q * 4 + rr;
      size_t rb = (size_t)row * U_SZ + n0 + wn * 64 + m;
#pragma unroll
      for (int nt = 0; nt < 4; ++nt)
        unsafeAtomicAdd(&out[rb + nt * 16], acc[mt][nt][rr]);
    }
}

extern "C" void kernel_launch(void* const* d_in, const int* in_sizes, int n_in,
                              void* d_out, int out_size, void* d_ws, size_t ws_size,
                              hipStream_t stream) {
  const float* X    = (const float*)d_in[0];  // (1024, 512)
  const float* SK   = (const float*)d_in[1];  // (512, 8, 512)
  const float* SF   = (const float*)d_in[2];  // (512, 512)
  const float* bias = (const float*)d_in[3];  // (512,)

  char* ws = (char*)d_ws;
  u16* WT = (u16*)ws;                 // 512*4608*2  = 4,718,592 B
  u16* A  = (u16*)(ws + 4718592);     // 1024*4608*2 = 9,437,184 B
  float* out = (float*)d_out;

  hipLaunchKernelGGL(prep_all, dim3(3072),     dim3(256), 0, stream,
                     SK, SF, X, bias, WT, A, out);
  hipLaunchKernelGGL(gemm_kan, dim3(8, 4, 16), dim3(256), 0, stream, A, WT, out);
}

// Round 4
// 92.407 us; speedup vs baseline: 1.1636x; 1.1636x over previous
//
#include <hip/hip_runtime.h>
#include <cstdint>
#include <cmath>

typedef unsigned short u16;
typedef __bf16 bf16x8 __attribute__((ext_vector_type(8)));
typedef float f32x4 __attribute__((ext_vector_type(4)));

#define B_SZ   1024
#define IN_SZ  512
#define U_SZ   512
#define KTOT   4608      // IN_SZ * 9 (8 spline bases + 1 silu slot)
#define SPLITS 8
#define KLEN   576       // KTOT / SPLITS
#define BK     32
#define KITERS 18        // KLEN / BK

__device__ __forceinline__ u16 f2bf(float f) {
  __bf16 h = (__bf16)f;
  return __builtin_bit_cast(u16, h);
}

// async global->LDS, 16B per lane. LDS dest must be wave-uniform base + lane*16.
__device__ __forceinline__ void async16(const void* g, void* l) {
  __builtin_amdgcn_global_load_lds(
      (__attribute__((address_space(1))) void*)(g),
      (__attribute__((address_space(3))) void*)(l), 16u, 0, 0u);
}

// ---------------------------------------------------------------------------
// One fused prep launch, grid-partitioned by blockIdx.x:
//   [0,512):    W'[o][i*9+k] = (k<8 ? SK[i][k][o] : 1)*SF[i][o], O-major (LDS
//               transpose, pad 66 so the strided read is conflict-free)
//   [512,2560): A[b][i*9+k] = cubic B-spline bases + silu (LDS-staged so the
//               global write is coalesced u16 streams, not 9x2B scalar)
// ---------------------------------------------------------------------------
__global__ void __launch_bounds__(256) prep_all(const float* __restrict__ SK,
                                                const float* __restrict__ SF,
                                                const float* __restrict__ X,
                                                u16* __restrict__ WT,
                                                u16* __restrict__ A) {
  const int bx = blockIdx.x;
  const int tid = threadIdx.x;

  if (bx < 512) {
    __shared__ u16 tile[72 * 66];
    const int o0 = (bx & 7) * 64;
    const int i0 = (bx >> 3) * 8;
    const int oo = tid & 63, grp = tid >> 6;
    for (int tr = grp; tr < 72; tr += 4) {
      int i = i0 + tr / 9;
      int k = tr % 9;
      float sf = SF[(size_t)i * U_SZ + o0 + oo];
      float v  = (k < 8) ? SK[((size_t)i * 8 + k) * U_SZ + o0 + oo] * sf : sf;
      tile[tr * 66 + oo] = f2bf(v);
    }
    __syncthreads();
    const int t0 = i0 * 9;
    for (int idx = tid; idx < 72 * 64; idx += 256) {
      int ol = idx / 72;
      int c  = idx - ol * 72;
      WT[(size_t)(o0 + ol) * KTOT + t0 + c] = tile[c * 66 + ol];
    }
  } else {
    __shared__ u16 st[2304];
    const int gid0 = (bx - 512) * 256;          // first (b*512+i) of this block
    const float x = X[gid0 + tid];

    const float T0 = -2.2f, H = 0.4f;
    float b0[11], b1[10], b2[9], b3[8];
#pragma unroll
    for (int j = 0; j < 11; ++j) {
      float tj  = T0 + H * j;
      float tj1 = T0 + H * (j + 1);
      b0[j] = (x >= tj && x < tj1) ? 1.0f : 0.0f;
    }
#pragma unroll
    for (int j = 0; j < 10; ++j) {
      float tj  = T0 + H * j;
      float tj2 = T0 + H * (j + 2);
      b1[j] = (x - tj) * 2.5f * b0[j] + (tj2 - x) * 2.5f * b0[j + 1];
    }
#pragma unroll
    for (int j = 0; j < 9; ++j) {
      float tj  = T0 + H * j;
      float tj3 = T0 + H * (j + 3);
      b2[j] = (x - tj) * 1.25f * b1[j] + (tj3 - x) * 1.25f * b1[j + 1];
    }
#pragma unroll
    for (int j = 0; j < 8; ++j) {
      float tj  = T0 + H * j;
      float tj4 = T0 + H * (j + 4);
      b3[j] = (x - tj) * (1.0f / 1.2f) * b2[j] + (tj4 - x) * (1.0f / 1.2f) * b2[j + 1];
    }
    float sil = x / (1.0f + expf(-x));

#pragma unroll
    for (int k = 0; k < 8; ++k) st[tid * 9 + k] = f2bf(b3[k]);
    st[tid * 9 + 8] = f2bf(sil);
    __syncthreads();
    u16* dst = A + (size_t)gid0 * 9;
#pragma unroll
    for (int j = 0; j < 9; ++j) dst[j * 256 + tid] = st[j * 256 + tid];
  }
}

// ---------------------------------------------------------------------------
// Split-K bf16 MFMA GEMM: P[s] = A[m0:+128, ks] * WT[n0:+128, ks]^T
// 256 threads = 4 waves in 2x2; each wave a 64x64 subtile (4x4 frags of
// 16x16x32). BK=32, double-buffered LDS with XOR-chunk swizzle (bank-optimal
// frag reads), global_load_lds width-16 staging. grid (8,4,8) x 256.
// (Atomic epilogue reverted: ~8.4M uncoalesced fp32 atomics serialize at TCC
//  channels ~27us — R3 post-mortem.)
// ---------------------------------------------------------------------------
__global__ void __launch_bounds__(256) gemm_kan(const u16* __restrict__ A,
                                                const u16* __restrict__ WT,
                                                float* __restrict__ P) {
  __shared__ __align__(16) u16 sA[2][128 * BK];   // 8 KB each buf
  __shared__ __align__(16) u16 sB[2][128 * BK];

  const int t    = threadIdx.x;
  const int lane = t & 63;
  const int w    = t >> 6;
  const int wr   = w >> 1;          // wave m-half (0/1)
  const int wn   = w & 1;           // wave n-half (0/1)
  const int m0   = blockIdx.x * 128;
  const int n0   = blockIdx.y * 128;
  const int kbase = blockIdx.z * KLEN;

  // staging: idx = j*256+t -> (row = idx>>2, c = idx&3); LDS pos (row,c) gets
  // global chunk g = c ^ (row&3). Dest offset idx*16 = wave-uniform + lane*16.
  const int srow = t >> 2, sc = t & 3;
  const int sg0 = (sc ^ (srow & 3)) * 8;              // element offset of chunk
  const int srow1 = (t + 256) >> 2, sc1 = t & 3;      // j=1: row += 64
  const int sg1 = (sc1 ^ (srow1 & 3)) * 8;
  const u16* gA0 = A  + (size_t)(m0 + srow)  * KTOT + sg0;
  const u16* gA1 = A  + (size_t)(m0 + srow1) * KTOT + sg1;
  const u16* gB0 = WT + (size_t)(n0 + srow)  * KTOT + sg0;
  const u16* gB1 = WT + (size_t)(n0 + srow1) * KTOT + sg1;

  f32x4 acc[4][4];
#pragma unroll
  for (int i = 0; i < 4; ++i)
#pragma unroll
    for (int j = 0; j < 4; ++j) acc[i][j] = (f32x4)0.0f;

  auto stage = [&](int buf, int k0) {
    char* lA = (char*)(&sA[buf][0]) + t * 16;
    char* lB = (char*)(&sB[buf][0]) + t * 16;
    async16(gA0 + k0, lA);
    async16(gA1 + k0, lA + 4096);
    async16(gB0 + k0, lB);
    async16(gB1 + k0, lB + 4096);
  };

  stage(0, kbase);

  const int m = lane & 15, q = lane >> 4;
  // frag read: row = half*64 + tt*16 + m; chunk pos = q ^ (row&3) = q ^ (m&3)
  const int qs = (q ^ (m & 3)) * 16;   // byte offset within row
  const char* fA = (const char*)(&sA[0][0]) + (wr * 64 + m) * (BK * 2) + qs;
  const char* fB = (const char*)(&sB[0][0]) + (wn * 64 + m) * (BK * 2) + qs;
  const int bufstep = 128 * BK * 2;    // bytes between dbuf buffers

#pragma unroll
  for (int it = 0; it < KITERS; ++it) {
    const int cur = it & 1;
    __syncthreads();                   // drains vmcnt: buf[cur] ready
    if (it + 1 < KITERS) stage(cur ^ 1, kbase + (it + 1) * BK);

    bf16x8 af[4], bfv[4];
#pragma unroll
    for (int tt = 0; tt < 4; ++tt)
      af[tt] = *(const bf16x8*)(fA + cur * bufstep + tt * 16 * (BK * 2));
#pragma unroll
    for (int tt = 0; tt < 4; ++tt)
      bfv[tt] = *(const bf16x8*)(fB + cur * bufstep + tt * 16 * (BK * 2));
#pragma unroll
    for (int mt = 0; mt < 4; ++mt)
#pragma unroll
      for (int nt = 0; nt < 4; ++nt)
        acc[mt][nt] = __builtin_amdgcn_mfma_f32_16x16x32_bf16(
            af[mt], bfv[nt], acc[mt][nt], 0, 0, 0);
  }

  // epilogue: C/D layout col = lane&15, row = (lane>>4)*4 + reg
  float* Pp = P + (size_t)blockIdx.z * (B_SZ * U_SZ);
#pragma unroll
  for (int mt = 0; mt < 4; ++mt)
#pragma unroll
    for (int rr = 0; rr < 4; ++rr) {
      int row = m0 + wr * 64 + mt * 16 + q * 4 + rr;
      size_t rb = (size_t)row * U_SZ + n0 + wn * 64 + m;
#pragma unroll
      for (int nt = 0; nt < 4; ++nt) Pp[rb + nt * 16] = acc[mt][nt][rr];
    }
}

// ---------------------------------------------------------------------------
// out = sum_s P[s] + bias. grid 512 x 256, float4 per thread.
// ---------------------------------------------------------------------------
__global__ void reduce_kernel(const float* __restrict__ P,
                              const float* __restrict__ bias,
                              float* __restrict__ out) {
  const int idx = blockIdx.x * 256 + threadIdx.x;  // float4 index, 0..131071
  const f32x4* P4 = (const f32x4*)P;
  f32x4 acc = P4[idx];
#pragma unroll
  for (int s = 1; s < SPLITS; ++s) acc += P4[(size_t)s * (B_SZ * U_SZ / 4) + idx];
  acc += ((const f32x4*)bias)[idx & 127];
  ((f32x4*)out)[idx] = acc;
}

extern "C" void kernel_launch(void* const* d_in, const int* in_sizes, int n_in,
                              void* d_out, int out_size, void* d_ws, size_t ws_size,
                              hipStream_t stream) {
  const float* X    = (const float*)d_in[0];  // (1024, 512)
  const float* SK   = (const float*)d_in[1];  // (512, 8, 512)
  const float* SF   = (const float*)d_in[2];  // (512, 512)
  const float* bias = (const float*)d_in[3];  // (512,)

  char* ws = (char*)d_ws;
  u16*   WT = (u16*)ws;                                    // 512*4608*2  = 4,718,592 B
  u16*   A  = (u16*)(ws + 4718592);                        // 1024*4608*2 = 9,437,184 B
  float* P  = (float*)(ws + 4718592 + 9437184);            // 8*1024*512*4 = 16,777,216 B

  hipLaunchKernelGGL(prep_all,      dim3(2560),    dim3(256), 0, stream, SK, SF, X, WT, A);
  hipLaunchKernelGGL(gemm_kan,      dim3(8, 4, 8), dim3(256), 0, stream, A, WT, P);
  hipLaunchKernelGGL(reduce_kernel, dim3(512),     dim3(256), 0, stream, P, bias, (float*)d_out);
}